// Round 5
// baseline (983.686 us; speedup 1.0000x reference)
//
#include <hip/hip_runtime.h>
#include <hip/hip_bf16.h>

#define NFEAT 512
#define NHID  64
#define NCLASS 40

typedef __attribute__((ext_vector_type(8))) __bf16 bf16x8;
typedef __attribute__((ext_vector_type(4))) float  f32x4;

// ---------------- W1 -> W1t (bf16, transposed [NHID][NFEAT]) ----------------
__global__ void k_w1t(const float* __restrict__ W1, __bf16* __restrict__ W1t) {
    int idx = blockIdx.x * 256 + threadIdx.x;
    if (idx >= NFEAT * NHID) return;
    int n = idx & (NHID - 1);
    int k = idx >> 6;
    W1t[(size_t)n * NFEAT + k] = (__bf16)W1[(size_t)k * NHID + n];
}

// ---------------- fused histogram: adj rows then pvt rows ----------------
__global__ void k_hist2(const int* __restrict__ arow, int E,
                        const int* __restrict__ prow, int E2,
                        int* __restrict__ cntA, int* __restrict__ cntP) {
    int i = blockIdx.x * 256 + threadIdx.x;
    if (i < E) atomicAdd(&cntA[arow[i]], 1);
    else if (i < E + E2) atomicAdd(&cntP[prow[i - E]], 1);
}

// ---------------- chunked scan: 2 blocks (adj / pvt), ~3 barriers total ----
__global__ __launch_bounds__(1024) void k_scan(
        const int* __restrict__ cntA, int* __restrict__ rpA, int* __restrict__ curA,
        const int* __restrict__ cntP, int* __restrict__ rpP, int* __restrict__ curP,
        int n) {
    const int* cnt = blockIdx.x ? cntP : cntA;
    int* rp  = blockIdx.x ? rpP  : rpA;
    int* cur = blockIdx.x ? curP : curA;
    __shared__ int wsum[16];
    const int tid = threadIdx.x;
    const int lane = tid & 63, w = tid >> 6;
    const int chunk = (n + 1023) >> 10;
    const int lo = tid * chunk;
    const int hi = min(lo + chunk, n);
    int s = 0;
    for (int i = lo; i < hi; ++i) s += cnt[i];
    int incl = s;
    #pragma unroll
    for (int o = 1; o < 64; o <<= 1) { int t = __shfl_up(incl, o, 64); if (lane >= o) incl += t; }
    if (lane == 63) wsum[w] = incl;
    __syncthreads();
    if (w == 0) {
        int xv = (lane < 16) ? wsum[lane] : 0;
        #pragma unroll
        for (int o = 1; o < 16; o <<= 1) { int t = __shfl_up(xv, o, 64); if (lane >= o) xv += t; }
        if (lane < 16) wsum[lane] = xv;
    }
    __syncthreads();
    int running = (w ? wsum[w - 1] : 0) + incl - s;
    for (int i = lo; i < hi; ++i) { rp[i] = running; cur[i] = running; running += cnt[i]; }
    if (tid == 1023) rp[n] = wsum[15];
}

// ---------------- fused scatter: packed int2 {col, val_bits} ----------------
__global__ void k_scat2(const int* __restrict__ arow, const int* __restrict__ acol,
                        const float* __restrict__ aval, int E,
                        const int* __restrict__ prow, const int* __restrict__ pcol,
                        const float* __restrict__ pval, int E2,
                        int* __restrict__ curA, int2* __restrict__ ccvA,
                        int* __restrict__ curP, int2* __restrict__ ccvP) {
    int i = blockIdx.x * 256 + threadIdx.x;
    if (i < E) {
        int p = atomicAdd(&curA[arow[i]], 1);
        ccvA[p] = make_int2(acol[i], __float_as_int(aval[i]));
    } else if (i < E + E2) {
        int j = i - E;
        int p = atomicAdd(&curP[prow[j]], 1);
        ccvP[p] = make_int2(pcol[j], __float_as_int(pval[j]));
    }
}

// ---------------- GEMM1: xw = bf16(x) @ bf16(W1), MFMA ----------------
__global__ __launch_bounds__(256) void k_gemm1(const float* __restrict__ x,
        const __bf16* __restrict__ W1t, __bf16* __restrict__ xw, int N) {
    __shared__ __align__(16) __bf16 xs[64][64];
    __shared__ __align__(16) __bf16 ws[64][64];
    const int t = threadIdx.x;
    const int lane = t & 63;
    const int w = t >> 6;
    const int wr = (w >> 1) * 32;
    const int wc = (w & 1) * 32;
    const int l15 = lane & 15;
    const int l4  = lane >> 4;
    const int row0 = blockIdx.x * 64;

    f32x4 acc[2][2] = {};

    for (int k0 = 0; k0 < NFEAT; k0 += 64) {
        #pragma unroll
        for (int s = t; s < 512; s += 256) {
            int r = s >> 3, ch = s & 7;
            int gr = row0 + r;
            float v[8] = {0.f,0.f,0.f,0.f,0.f,0.f,0.f,0.f};
            if (gr < N) {
                const float4* p = (const float4*)(x + (size_t)gr * NFEAT + k0 + ch * 8);
                float4 a0 = p[0], a1 = p[1];
                v[0]=a0.x; v[1]=a0.y; v[2]=a0.z; v[3]=a0.w;
                v[4]=a1.x; v[5]=a1.y; v[6]=a1.z; v[7]=a1.w;
            }
            bf16x8 frag;
            #pragma unroll
            for (int j = 0; j < 8; ++j) frag[j] = (__bf16)v[j];
            *(bf16x8*)&xs[r][((ch ^ (r & 7)) * 8)] = frag;
        }
        #pragma unroll
        for (int s = t; s < 512; s += 256) {
            int n = s >> 3, ch = s & 7;
            bf16x8 frag = *(const bf16x8*)(W1t + (size_t)n * NFEAT + k0 + ch * 8);
            *(bf16x8*)&ws[n][((ch ^ (n & 7)) * 8)] = frag;
        }
        __syncthreads();
        #pragma unroll
        for (int kh = 0; kh < 2; ++kh) {
            bf16x8 a[2], b[2];
            #pragma unroll
            for (int mi = 0; mi < 2; ++mi) {
                int r = wr + mi * 16 + l15;
                int ch = (kh * 4 + l4) ^ (r & 7);
                a[mi] = *(const bf16x8*)&xs[r][ch * 8];
            }
            #pragma unroll
            for (int ni = 0; ni < 2; ++ni) {
                int n = wc + ni * 16 + l15;
                int ch = (kh * 4 + l4) ^ (n & 7);
                b[ni] = *(const bf16x8*)&ws[n][ch * 8];
            }
            #pragma unroll
            for (int mi = 0; mi < 2; ++mi)
                #pragma unroll
                for (int ni = 0; ni < 2; ++ni)
                    acc[mi][ni] = __builtin_amdgcn_mfma_f32_16x16x32_bf16(a[mi], b[ni], acc[mi][ni], 0, 0, 0);
        }
        __syncthreads();
    }
    #pragma unroll
    for (int mi = 0; mi < 2; ++mi)
        #pragma unroll
        for (int ni = 0; ni < 2; ++ni)
            #pragma unroll
            for (int j = 0; j < 4; ++j) {
                int r = row0 + wr + mi * 16 + l4 * 4 + j;
                int c = wc + ni * 16 + l15;
                if (r < N) xw[(size_t)r * NHID + c] = (__bf16)acc[mi][ni][j];
            }
}

// ---------------- SPMM1: h1 = relu(adj @ xw + b1) ----------------
__global__ void k_spmm1(const int* __restrict__ rp, const int2* __restrict__ ccv,
        const __bf16* __restrict__ xw, const float* __restrict__ b1,
        float* __restrict__ h1, int N) {
    int lane = threadIdx.x & 63;
    int row = blockIdx.x * 4 + (threadIdx.x >> 6);
    if (row >= N) return;
    int e = rp[row], end = rp[row + 1];
    float acc = 0.f;
    for (; e + 1 < end; e += 2) {
        int2 a = ccv[e], b = ccv[e + 1];
        acc += __int_as_float(a.y) * (float)xw[(size_t)a.x * NHID + lane];
        acc += __int_as_float(b.y) * (float)xw[(size_t)b.x * NHID + lane];
    }
    if (e < end) {
        int2 a = ccv[e];
        acc += __int_as_float(a.y) * (float)xw[(size_t)a.x * NHID + lane];
    }
    h1[(size_t)row * NHID + lane] = fmaxf(acc + b1[lane], 0.f);
}

// ---------------- GEMM2: hw = bf16(h1 @ W2) ----------------
__global__ __launch_bounds__(128) void k_gemm2(const float* __restrict__ h1,
        const float* __restrict__ W2, __bf16* __restrict__ hw, int N) {
    __shared__ float w2s[NHID * NCLASS];
    for (int i = threadIdx.x; i < NHID * NCLASS; i += 128) w2s[i] = W2[i];
    __syncthreads();
    int row = blockIdx.x * 128 + threadIdx.x;
    if (row >= N) return;
    float acc[NCLASS];
    #pragma unroll
    for (int c = 0; c < NCLASS; ++c) acc[c] = 0.f;
    const float4* hp = (const float4*)(h1 + (size_t)row * NHID);
    #pragma unroll
    for (int k4 = 0; k4 < NHID / 4; ++k4) {
        float4 a = hp[k4];
        const float* wr0 = &w2s[(k4 * 4) * NCLASS];
        #pragma unroll
        for (int c = 0; c < NCLASS; ++c)
            acc[c] += a.x * wr0[c] + a.y * wr0[NCLASS + c]
                    + a.z * wr0[2 * NCLASS + c] + a.w * wr0[3 * NCLASS + c];
    }
    // 40 bf16 = 80 B per row, 16B-aligned (80 % 16 == 0): 5 x bf16x8 stores
    bf16x8* op = (bf16x8*)(hw + (size_t)row * NCLASS);
    #pragma unroll
    for (int c8 = 0; c8 < NCLASS / 8; ++c8) {
        bf16x8 o;
        #pragma unroll
        for (int j = 0; j < 8; ++j) o[j] = (__bf16)acc[c8 * 8 + j];
        op[c8] = o;
    }
}

// ---------------- SPMM2: h2 = adj @ hw + b2 ----------------
__global__ void k_spmm2(const int* __restrict__ rp, const int2* __restrict__ ccv,
        const __bf16* __restrict__ hw, const float* __restrict__ b2,
        float* __restrict__ h2, int N) {
    int lane = threadIdx.x & 63;
    int row = blockIdx.x * 4 + (threadIdx.x >> 6);
    if (row >= N) return;
    if (lane >= NCLASS) return;
    int e = rp[row], end = rp[row + 1];
    float acc = 0.f;
    for (; e + 1 < end; e += 2) {
        int2 a = ccv[e], b = ccv[e + 1];
        acc += __int_as_float(a.y) * (float)hw[(size_t)a.x * NCLASS + lane];
        acc += __int_as_float(b.y) * (float)hw[(size_t)b.x * NCLASS + lane];
    }
    if (e < end) {
        int2 a = ccv[e];
        acc += __int_as_float(a.y) * (float)hw[(size_t)a.x * NCLASS + lane];
    }
    h2[(size_t)row * NCLASS + lane] = acc + b2[lane];
}

// ---------------- fused PvT spmm (CSR, no atomics) + log_softmax -----------
__global__ void k_pvt_lsm(const int* __restrict__ rp, const int2* __restrict__ ccv,
        const float* __restrict__ h2, float* __restrict__ out, int N) {
    int lane = threadIdx.x & 63;
    int row = blockIdx.x * 4 + (threadIdx.x >> 6);
    if (row >= N) return;
    float acc = 0.f;
    if (lane < NCLASS) {
        int e = rp[row], end = rp[row + 1];
        for (; e < end; ++e) {
            int2 a = ccv[e];
            acc += __int_as_float(a.y) * h2[(size_t)a.x * NCLASS + lane];
        }
    }
    float v = (lane < NCLASS) ? acc : -__builtin_inff();
    float m = v;
    #pragma unroll
    for (int o = 32; o; o >>= 1) m = fmaxf(m, __shfl_xor(m, o, 64));
    float ex = (lane < NCLASS) ? expf(v - m) : 0.f;
    float s = ex;
    #pragma unroll
    for (int o = 32; o; o >>= 1) s += __shfl_xor(s, o, 64);
    if (lane < NCLASS) out[(size_t)row * NCLASS + lane] = v - m - logf(s);
}

extern "C" void kernel_launch(void* const* d_in, const int* in_sizes, int n_in,
                              void* d_out, int out_size, void* d_ws, size_t ws_size,
                              hipStream_t stream) {
    const float* x       = (const float*)d_in[0];
    const int*   adj_row = (const int*)d_in[1];
    const int*   adj_col = (const int*)d_in[2];
    const float* adj_val = (const float*)d_in[3];
    const int*   pvt_row = (const int*)d_in[4];
    const int*   pvt_col = (const int*)d_in[5];
    const float* pvt_val = (const float*)d_in[6];
    const float* W1      = (const float*)d_in[7];
    const float* b1      = (const float*)d_in[8];
    const float* W2      = (const float*)d_in[9];
    const float* b2      = (const float*)d_in[10];
    const int N  = in_sizes[0] / NFEAT;
    const int E  = in_sizes[1];
    const int E2 = in_sizes[4];
    float* out = (float*)d_out;

    char* p = (char*)d_ws;
    auto alloc = [&](size_t bytes) { char* q = p; p += (bytes + 255) & ~(size_t)255; return q; };
    // unionA: xw (bf16, 12.8MB) then hw (bf16, 8MB)
    char* uA = alloc((size_t)N * NHID * 2);
    __bf16* xw = (__bf16*)uA;
    __bf16* hw = (__bf16*)uA;
    // unionB: h1 (f32, 25.6MB) then h2 (f32, 16MB)
    char* uB = alloc((size_t)N * NHID * 4);
    float* h1 = (float*)uB;
    float* h2 = (float*)uB;
    int*    cnt2 = (int*)alloc((size_t)2 * N * 4);       // cntA | cntP
    int*    cntA = cnt2;
    int*    cntP = cnt2 + N;
    int*    rpA  = (int*)alloc(((size_t)N + 1) * 4);
    int*    rpP  = (int*)alloc(((size_t)N + 1) * 4);
    int*    curA = (int*)alloc((size_t)N * 4);
    int*    curP = (int*)alloc((size_t)N * 4);
    int2*   ccvA = (int2*)alloc((size_t)E * 8);
    int2*   ccvP = (int2*)alloc((size_t)E2 * 8);
    __bf16* W1t  = (__bf16*)alloc((size_t)NFEAT * NHID * 2);
    (void)ws_size; (void)n_in; (void)out_size;

    hipMemsetAsync(cnt2, 0, (size_t)2 * N * 4, stream);
    k_w1t<<<(NFEAT * NHID + 255) / 256, 256, 0, stream>>>(W1, W1t);
    k_hist2<<<(E + E2 + 255) / 256, 256, 0, stream>>>(adj_row, E, pvt_row, E2, cntA, cntP);
    k_scan<<<2, 1024, 0, stream>>>(cntA, rpA, curA, cntP, rpP, curP, N);
    k_scat2<<<(E + E2 + 255) / 256, 256, 0, stream>>>(adj_row, adj_col, adj_val, E,
                                                      pvt_row, pvt_col, pvt_val, E2,
                                                      curA, ccvA, curP, ccvP);
    k_gemm1<<<(N + 63) / 64, 256, 0, stream>>>(x, W1t, xw, N);
    k_spmm1<<<(N + 3) / 4, 256, 0, stream>>>(rpA, ccvA, xw, b1, h1, N);
    k_gemm2<<<(N + 127) / 128, 128, 0, stream>>>(h1, W2, hw, N);
    k_spmm2<<<(N + 3) / 4, 256, 0, stream>>>(rpA, ccvA, hw, b2, h2, N);
    k_pvt_lsm<<<(N + 3) / 4, 256, 0, stream>>>(rpP, ccvP, h2, out, N);
}

// Round 6
// 771.863 us; speedup vs baseline: 1.2744x; 1.2744x over previous
//
#include <hip/hip_runtime.h>
#include <hip/hip_bf16.h>

#define NFEAT 512
#define NHID  64
#define NCLASS 40

typedef __attribute__((ext_vector_type(8))) __bf16 bf16x8;
typedef __attribute__((ext_vector_type(4))) float  f32x4;

// ---------------- W1 -> W1t (bf16, transposed [NHID][NFEAT]) ----------------
__global__ void k_w1t(const float* __restrict__ W1, __bf16* __restrict__ W1t) {
    int idx = blockIdx.x * 256 + threadIdx.x;
    if (idx >= NFEAT * NHID) return;
    int n = idx & (NHID - 1);
    int k = idx >> 6;
    W1t[(size_t)n * NFEAT + k] = (__bf16)W1[(size_t)k * NHID + n];
}

// ---------------- fused histogram: adj rows then pvt rows ----------------
__global__ void k_hist2(const int* __restrict__ arow, int E,
                        const int* __restrict__ prow, int E2,
                        int* __restrict__ cntA, int* __restrict__ cntP) {
    int i = blockIdx.x * 256 + threadIdx.x;
    if (i < E) atomicAdd(&cntA[arow[i]], 1);
    else if (i < E + E2) atomicAdd(&cntP[prow[i - E]], 1);
}

// ---------------- coalesced 3-phase scan ----------------
// phase 1: per-block (1024-wide) exclusive scan + block sums. grid=(nblk,2)
__global__ __launch_bounds__(1024) void k_scan1(
        const int* __restrict__ cntA, int* __restrict__ exclA, int* __restrict__ bsumA,
        const int* __restrict__ cntP, int* __restrict__ exclP, int* __restrict__ bsumP,
        int n) {
    const int* cnt = blockIdx.y ? cntP : cntA;
    int* excl = blockIdx.y ? exclP : exclA;
    int* bsum = blockIdx.y ? bsumP : bsumA;
    __shared__ int wsum[16];
    const int tid = threadIdx.x, lane = tid & 63, w = tid >> 6;
    int i = blockIdx.x * 1024 + tid;
    int v = (i < n) ? cnt[i] : 0;
    int incl = v;
    #pragma unroll
    for (int o = 1; o < 64; o <<= 1) { int t = __shfl_up(incl, o, 64); if (lane >= o) incl += t; }
    if (lane == 63) wsum[w] = incl;
    __syncthreads();
    if (w == 0) {
        int xv = (lane < 16) ? wsum[lane] : 0;
        #pragma unroll
        for (int o = 1; o < 16; o <<= 1) { int t = __shfl_up(xv, o, 64); if (lane >= o) xv += t; }
        if (lane < 16) wsum[lane] = xv;
    }
    __syncthreads();
    if (i < n) excl[i] = (w ? wsum[w - 1] : 0) + incl - v;
    if (tid == 1023) bsum[blockIdx.x] = wsum[15];
}

// phase 2: scan block sums (nblk <= 1024). grid=(2)
__global__ __launch_bounds__(1024) void k_scan2(
        int* __restrict__ bsumA, int* __restrict__ bsumP, int nblk) {
    int* bs = blockIdx.x ? bsumP : bsumA;
    __shared__ int wsum[16];
    const int tid = threadIdx.x, lane = tid & 63, w = tid >> 6;
    int v = (tid < nblk) ? bs[tid] : 0;
    int incl = v;
    #pragma unroll
    for (int o = 1; o < 64; o <<= 1) { int t = __shfl_up(incl, o, 64); if (lane >= o) incl += t; }
    if (lane == 63) wsum[w] = incl;
    __syncthreads();
    if (w == 0) {
        int xv = (lane < 16) ? wsum[lane] : 0;
        #pragma unroll
        for (int o = 1; o < 16; o <<= 1) { int t = __shfl_up(xv, o, 64); if (lane >= o) xv += t; }
        if (lane < 16) wsum[lane] = xv;
    }
    __syncthreads();
    if (tid < nblk) bs[tid] = (w ? wsum[w - 1] : 0) + incl - v;   // exclusive
    if (tid == 1023) bs[nblk] = wsum[15];                          // total
}

// phase 3: rp[i] = excl[i] + boff[blk]; cur likewise; rp[n] = total. grid=(nblk,2)
__global__ __launch_bounds__(1024) void k_scan3(
        const int* __restrict__ exclA, const int* __restrict__ bsumA,
        int* __restrict__ rpA, int* __restrict__ curA,
        const int* __restrict__ exclP, const int* __restrict__ bsumP,
        int* __restrict__ rpP, int* __restrict__ curP,
        int n, int nblk) {
    const int* excl = blockIdx.y ? exclP : exclA;
    const int* bsum = blockIdx.y ? bsumP : bsumA;
    int* rp  = blockIdx.y ? rpP  : rpA;
    int* cur = blockIdx.y ? curP : curA;
    int i = blockIdx.x * 1024 + threadIdx.x;
    if (i < n) {
        int r = excl[i] + bsum[blockIdx.x];
        rp[i] = r;
        cur[i] = r;
    }
    if (blockIdx.x == 0 && threadIdx.x == 0) rp[n] = bsum[nblk];
}

// ---------------- fused scatter: packed int2 {col, val_bits} ----------------
__global__ void k_scat2(const int* __restrict__ arow, const int* __restrict__ acol,
                        const float* __restrict__ aval, int E,
                        const int* __restrict__ prow, const int* __restrict__ pcol,
                        const float* __restrict__ pval, int E2,
                        int* __restrict__ curA, int2* __restrict__ ccvA,
                        int* __restrict__ curP, int2* __restrict__ ccvP) {
    int i = blockIdx.x * 256 + threadIdx.x;
    if (i < E) {
        int p = atomicAdd(&curA[arow[i]], 1);
        ccvA[p] = make_int2(acol[i], __float_as_int(aval[i]));
    } else if (i < E + E2) {
        int j = i - E;
        int p = atomicAdd(&curP[prow[j]], 1);
        ccvP[p] = make_int2(pcol[j], __float_as_int(pval[j]));
    }
}

// ---------------- GEMM1: xw = bf16(x) @ bf16(W1), MFMA ----------------
__global__ __launch_bounds__(256) void k_gemm1(const float* __restrict__ x,
        const __bf16* __restrict__ W1t, __bf16* __restrict__ xw, int N) {
    __shared__ __align__(16) __bf16 xs[64][64];
    __shared__ __align__(16) __bf16 ws[64][64];
    const int t = threadIdx.x;
    const int lane = t & 63;
    const int w = t >> 6;
    const int wr = (w >> 1) * 32;
    const int wc = (w & 1) * 32;
    const int l15 = lane & 15;
    const int l4  = lane >> 4;
    const int row0 = blockIdx.x * 64;

    f32x4 acc[2][2] = {};

    for (int k0 = 0; k0 < NFEAT; k0 += 64) {
        #pragma unroll
        for (int s = t; s < 512; s += 256) {
            int r = s >> 3, ch = s & 7;
            int gr = row0 + r;
            float v[8] = {0.f,0.f,0.f,0.f,0.f,0.f,0.f,0.f};
            if (gr < N) {
                const float4* p = (const float4*)(x + (size_t)gr * NFEAT + k0 + ch * 8);
                float4 a0 = p[0], a1 = p[1];
                v[0]=a0.x; v[1]=a0.y; v[2]=a0.z; v[3]=a0.w;
                v[4]=a1.x; v[5]=a1.y; v[6]=a1.z; v[7]=a1.w;
            }
            bf16x8 frag;
            #pragma unroll
            for (int j = 0; j < 8; ++j) frag[j] = (__bf16)v[j];
            *(bf16x8*)&xs[r][((ch ^ (r & 7)) * 8)] = frag;
        }
        #pragma unroll
        for (int s = t; s < 512; s += 256) {
            int n = s >> 3, ch = s & 7;
            bf16x8 frag = *(const bf16x8*)(W1t + (size_t)n * NFEAT + k0 + ch * 8);
            *(bf16x8*)&ws[n][((ch ^ (n & 7)) * 8)] = frag;
        }
        __syncthreads();
        #pragma unroll
        for (int kh = 0; kh < 2; ++kh) {
            bf16x8 a[2], b[2];
            #pragma unroll
            for (int mi = 0; mi < 2; ++mi) {
                int r = wr + mi * 16 + l15;
                int ch = (kh * 4 + l4) ^ (r & 7);
                a[mi] = *(const bf16x8*)&xs[r][ch * 8];
            }
            #pragma unroll
            for (int ni = 0; ni < 2; ++ni) {
                int n = wc + ni * 16 + l15;
                int ch = (kh * 4 + l4) ^ (n & 7);
                b[ni] = *(const bf16x8*)&ws[n][ch * 8];
            }
            #pragma unroll
            for (int mi = 0; mi < 2; ++mi)
                #pragma unroll
                for (int ni = 0; ni < 2; ++ni)
                    acc[mi][ni] = __builtin_amdgcn_mfma_f32_16x16x32_bf16(a[mi], b[ni], acc[mi][ni], 0, 0, 0);
        }
        __syncthreads();
    }
    #pragma unroll
    for (int mi = 0; mi < 2; ++mi)
        #pragma unroll
        for (int ni = 0; ni < 2; ++ni)
            #pragma unroll
            for (int j = 0; j < 4; ++j) {
                int r = row0 + wr + mi * 16 + l4 * 4 + j;
                int c = wc + ni * 16 + l15;
                if (r < N) xw[(size_t)r * NHID + c] = (__bf16)acc[mi][ni][j];
            }
}

// ---------------- SPMM1: h1 = relu(adj @ xw + b1) ----------------
__global__ void k_spmm1(const int* __restrict__ rp, const int2* __restrict__ ccv,
        const __bf16* __restrict__ xw, const float* __restrict__ b1,
        float* __restrict__ h1, int N) {
    int lane = threadIdx.x & 63;
    int row = blockIdx.x * 4 + (threadIdx.x >> 6);
    if (row >= N) return;
    int e = rp[row], end = rp[row + 1];
    float acc = 0.f;
    for (; e + 1 < end; e += 2) {
        int2 a = ccv[e], b = ccv[e + 1];
        acc += __int_as_float(a.y) * (float)xw[(size_t)a.x * NHID + lane];
        acc += __int_as_float(b.y) * (float)xw[(size_t)b.x * NHID + lane];
    }
    if (e < end) {
        int2 a = ccv[e];
        acc += __int_as_float(a.y) * (float)xw[(size_t)a.x * NHID + lane];
    }
    h1[(size_t)row * NHID + lane] = fmaxf(acc + b1[lane], 0.f);
}

// ---------------- GEMM2: hw = bf16(h1 @ W2) ----------------
__global__ __launch_bounds__(128) void k_gemm2(const float* __restrict__ h1,
        const float* __restrict__ W2, __bf16* __restrict__ hw, int N) {
    __shared__ float w2s[NHID * NCLASS];
    for (int i = threadIdx.x; i < NHID * NCLASS; i += 128) w2s[i] = W2[i];
    __syncthreads();
    int row = blockIdx.x * 128 + threadIdx.x;
    if (row >= N) return;
    float acc[NCLASS];
    #pragma unroll
    for (int c = 0; c < NCLASS; ++c) acc[c] = 0.f;
    const float4* hp = (const float4*)(h1 + (size_t)row * NHID);
    #pragma unroll
    for (int k4 = 0; k4 < NHID / 4; ++k4) {
        float4 a = hp[k4];
        const float* wr0 = &w2s[(k4 * 4) * NCLASS];
        #pragma unroll
        for (int c = 0; c < NCLASS; ++c)
            acc[c] += a.x * wr0[c] + a.y * wr0[NCLASS + c]
                    + a.z * wr0[2 * NCLASS + c] + a.w * wr0[3 * NCLASS + c];
    }
    // 40 bf16 = 80 B per row, 16B-aligned (80 % 16 == 0): 5 x bf16x8 stores
    bf16x8* op = (bf16x8*)(hw + (size_t)row * NCLASS);
    #pragma unroll
    for (int c8 = 0; c8 < NCLASS / 8; ++c8) {
        bf16x8 o;
        #pragma unroll
        for (int j = 0; j < 8; ++j) o[j] = (__bf16)acc[c8 * 8 + j];
        op[c8] = o;
    }
}

// ---------------- SPMM2: h2 = adj @ hw + b2 ----------------
__global__ void k_spmm2(const int* __restrict__ rp, const int2* __restrict__ ccv,
        const __bf16* __restrict__ hw, const float* __restrict__ b2,
        float* __restrict__ h2, int N) {
    int lane = threadIdx.x & 63;
    int row = blockIdx.x * 4 + (threadIdx.x >> 6);
    if (row >= N) return;
    if (lane >= NCLASS) return;
    int e = rp[row], end = rp[row + 1];
    float acc = 0.f;
    for (; e + 1 < end; e += 2) {
        int2 a = ccv[e], b = ccv[e + 1];
        acc += __int_as_float(a.y) * (float)hw[(size_t)a.x * NCLASS + lane];
        acc += __int_as_float(b.y) * (float)hw[(size_t)b.x * NCLASS + lane];
    }
    if (e < end) {
        int2 a = ccv[e];
        acc += __int_as_float(a.y) * (float)hw[(size_t)a.x * NCLASS + lane];
    }
    h2[(size_t)row * NCLASS + lane] = acc + b2[lane];
}

// ---------------- fused PvT spmm (CSR, no atomics) + log_softmax -----------
__global__ void k_pvt_lsm(const int* __restrict__ rp, const int2* __restrict__ ccv,
        const float* __restrict__ h2, float* __restrict__ out, int N) {
    int lane = threadIdx.x & 63;
    int row = blockIdx.x * 4 + (threadIdx.x >> 6);
    if (row >= N) return;
    float acc = 0.f;
    if (lane < NCLASS) {
        int e = rp[row], end = rp[row + 1];
        for (; e < end; ++e) {
            int2 a = ccv[e];
            acc += __int_as_float(a.y) * h2[(size_t)a.x * NCLASS + lane];
        }
    }
    float v = (lane < NCLASS) ? acc : -__builtin_inff();
    float m = v;
    #pragma unroll
    for (int o = 32; o; o >>= 1) m = fmaxf(m, __shfl_xor(m, o, 64));
    float ex = (lane < NCLASS) ? expf(v - m) : 0.f;
    float s = ex;
    #pragma unroll
    for (int o = 32; o; o >>= 1) s += __shfl_xor(s, o, 64);
    if (lane < NCLASS) out[(size_t)row * NCLASS + lane] = v - m - logf(s);
}

extern "C" void kernel_launch(void* const* d_in, const int* in_sizes, int n_in,
                              void* d_out, int out_size, void* d_ws, size_t ws_size,
                              hipStream_t stream) {
    const float* x       = (const float*)d_in[0];
    const int*   adj_row = (const int*)d_in[1];
    const int*   adj_col = (const int*)d_in[2];
    const float* adj_val = (const float*)d_in[3];
    const int*   pvt_row = (const int*)d_in[4];
    const int*   pvt_col = (const int*)d_in[5];
    const float* pvt_val = (const float*)d_in[6];
    const float* W1      = (const float*)d_in[7];
    const float* b1      = (const float*)d_in[8];
    const float* W2      = (const float*)d_in[9];
    const float* b2      = (const float*)d_in[10];
    const int N  = in_sizes[0] / NFEAT;
    const int E  = in_sizes[1];
    const int E2 = in_sizes[4];
    float* out = (float*)d_out;

    char* p = (char*)d_ws;
    auto alloc = [&](size_t bytes) { char* q = p; p += (bytes + 255) & ~(size_t)255; return q; };
    // unionA: xw (bf16, 12.8MB) then hw (bf16, 8MB)
    char* uA = alloc((size_t)N * NHID * 2);
    __bf16* xw = (__bf16*)uA;
    __bf16* hw = (__bf16*)uA;
    // unionB: h1 (f32, 25.6MB) then h2 (f32, 16MB)
    char* uB = alloc((size_t)N * NHID * 4);
    float* h1 = (float*)uB;
    float* h2 = (float*)uB;
    int*    cnt2 = (int*)alloc((size_t)2 * N * 4);       // cntA | cntP
    int*    cntA = cnt2;
    int*    cntP = cnt2 + N;
    int*    rpA  = (int*)alloc(((size_t)N + 1) * 4);
    int*    rpP  = (int*)alloc(((size_t)N + 1) * 4);
    int*    curA = (int*)alloc((size_t)N * 4);
    int*    curP = (int*)alloc((size_t)N * 4);
    int2*   ccvA = (int2*)alloc((size_t)E * 8);
    int2*   ccvP = (int2*)alloc((size_t)E2 * 8);
    __bf16* W1t  = (__bf16*)alloc((size_t)NFEAT * NHID * 2);
    int*    exclA = (int*)alloc((size_t)N * 4);
    int*    exclP = (int*)alloc((size_t)N * 4);
    const int nblk = (N + 1023) / 1024;
    int*    bsumA = (int*)alloc(((size_t)nblk + 1) * 4);
    int*    bsumP = (int*)alloc(((size_t)nblk + 1) * 4);
    (void)ws_size; (void)n_in; (void)out_size;

    hipMemsetAsync(cnt2, 0, (size_t)2 * N * 4, stream);
    k_w1t<<<(NFEAT * NHID + 255) / 256, 256, 0, stream>>>(W1, W1t);
    k_hist2<<<(E + E2 + 255) / 256, 256, 0, stream>>>(adj_row, E, pvt_row, E2, cntA, cntP);
    k_scan1<<<dim3(nblk, 2), 1024, 0, stream>>>(cntA, exclA, bsumA, cntP, exclP, bsumP, N);
    k_scan2<<<2, 1024, 0, stream>>>(bsumA, bsumP, nblk);
    k_scan3<<<dim3(nblk, 2), 1024, 0, stream>>>(exclA, bsumA, rpA, curA,
                                                exclP, bsumP, rpP, curP, N, nblk);
    k_scat2<<<(E + E2 + 255) / 256, 256, 0, stream>>>(adj_row, adj_col, adj_val, E,
                                                      pvt_row, pvt_col, pvt_val, E2,
                                                      curA, ccvA, curP, ccvP);
    k_gemm1<<<(N + 63) / 64, 256, 0, stream>>>(x, W1t, xw, N);
    k_spmm1<<<(N + 3) / 4, 256, 0, stream>>>(rpA, ccvA, xw, b1, h1, N);
    k_gemm2<<<(N + 127) / 128, 128, 0, stream>>>(h1, W2, hw, N);
    k_spmm2<<<(N + 3) / 4, 256, 0, stream>>>(rpA, ccvA, hw, b2, h2, N);
    k_pvt_lsm<<<(N + 3) / 4, 256, 0, stream>>>(rpP, ccvP, h2, out, N);
}

// Round 8
// 741.168 us; speedup vs baseline: 1.3272x; 1.0414x over previous
//
#include <hip/hip_runtime.h>
#include <hip/hip_bf16.h>

#define NFEAT 512
#define NHID  64
#define NCLASS 40
#define SCAT_CHUNK 4096

typedef __attribute__((ext_vector_type(8))) __bf16 bf16x8;
typedef __attribute__((ext_vector_type(4))) float  f32x4;

// ---------------- W1 -> W1t (bf16, transposed [NHID][NFEAT]) ----------------
__global__ void k_w1t(const float* __restrict__ W1, __bf16* __restrict__ W1t) {
    int idx = blockIdx.x * 256 + threadIdx.x;
    if (idx >= NFEAT * NHID) return;
    int n = idx & (NHID - 1);
    int k = idx >> 6;
    W1t[(size_t)n * NFEAT + k] = (__bf16)W1[(size_t)k * NHID + n];
}

// ---------------- XCD-segmented histogram ----------------
// block b: edge-chunk b>>3, row-segment b&7 (lands on XCD b&7 under
// round-robin dispatch -> cnt lines stay in one L2).
__global__ __launch_bounds__(256) void k_hist2(
        const int* __restrict__ arow, int E,
        const int* __restrict__ prow, int E2,
        int* __restrict__ cntA, int* __restrict__ cntP, int n) {
    const int seg = blockIdx.x & 7;
    const int seglen = (n + 7) >> 3;
    const int rlo = seg * seglen, rhi = rlo + seglen;
    const int base = (blockIdx.x >> 3) * SCAT_CHUNK;
    const int lim = min(base + SCAT_CHUNK, E + E2);
    for (int i = base + threadIdx.x; i < lim; i += 256) {
        if (i < E) {
            int r = __builtin_nontemporal_load(&arow[i]);
            if (r >= rlo && r < rhi) atomicAdd(&cntA[r], 1);
        } else {
            int r = __builtin_nontemporal_load(&prow[i - E]);
            if (r >= rlo && r < rhi) atomicAdd(&cntP[r], 1);
        }
    }
}

// ---------------- coalesced 3-phase scan ----------------
__global__ __launch_bounds__(1024) void k_scan1(
        const int* __restrict__ cntA, int* __restrict__ exclA, int* __restrict__ bsumA,
        const int* __restrict__ cntP, int* __restrict__ exclP, int* __restrict__ bsumP,
        int n) {
    const int* cnt = blockIdx.y ? cntP : cntA;
    int* excl = blockIdx.y ? exclP : exclA;
    int* bsum = blockIdx.y ? bsumP : bsumA;
    __shared__ int wsum[16];
    const int tid = threadIdx.x, lane = tid & 63, w = tid >> 6;
    int i = blockIdx.x * 1024 + tid;
    int v = (i < n) ? cnt[i] : 0;
    int incl = v;
    #pragma unroll
    for (int o = 1; o < 64; o <<= 1) { int t = __shfl_up(incl, o, 64); if (lane >= o) incl += t; }
    if (lane == 63) wsum[w] = incl;
    __syncthreads();
    if (w == 0) {
        int xv = (lane < 16) ? wsum[lane] : 0;
        #pragma unroll
        for (int o = 1; o < 16; o <<= 1) { int t = __shfl_up(xv, o, 64); if (lane >= o) xv += t; }
        if (lane < 16) wsum[lane] = xv;
    }
    __syncthreads();
    if (i < n) excl[i] = (w ? wsum[w - 1] : 0) + incl - v;
    if (tid == 1023) bsum[blockIdx.x] = wsum[15];
}

__global__ __launch_bounds__(1024) void k_scan2(
        int* __restrict__ bsumA, int* __restrict__ bsumP, int nblk) {
    int* bs = blockIdx.x ? bsumP : bsumA;
    __shared__ int wsum[16];
    const int tid = threadIdx.x, lane = tid & 63, w = tid >> 6;
    int v = (tid < nblk) ? bs[tid] : 0;
    int incl = v;
    #pragma unroll
    for (int o = 1; o < 64; o <<= 1) { int t = __shfl_up(incl, o, 64); if (lane >= o) incl += t; }
    if (lane == 63) wsum[w] = incl;
    __syncthreads();
    if (w == 0) {
        int xv = (lane < 16) ? wsum[lane] : 0;
        #pragma unroll
        for (int o = 1; o < 16; o <<= 1) { int t = __shfl_up(xv, o, 64); if (lane >= o) xv += t; }
        if (lane < 16) wsum[lane] = xv;
    }
    __syncthreads();
    if (tid < nblk) bs[tid] = (w ? wsum[w - 1] : 0) + incl - v;   // exclusive
    if (tid == 1023) bs[nblk] = wsum[15];                          // total
}

__global__ __launch_bounds__(1024) void k_scan3(
        const int* __restrict__ exclA, const int* __restrict__ bsumA,
        int* __restrict__ rpA, int* __restrict__ curA,
        const int* __restrict__ exclP, const int* __restrict__ bsumP,
        int* __restrict__ rpP, int* __restrict__ curP,
        int n, int nblk) {
    const int* excl = blockIdx.y ? exclP : exclA;
    const int* bsum = blockIdx.y ? bsumP : bsumA;
    int* rp  = blockIdx.y ? rpP  : rpA;
    int* cur = blockIdx.y ? curP : curA;
    int i = blockIdx.x * 1024 + threadIdx.x;
    if (i < n) {
        int r = excl[i] + bsum[blockIdx.x];
        rp[i] = r;
        cur[i] = r;
    }
    if (blockIdx.x == 0 && threadIdx.x == 0) rp[n] = bsum[nblk];
}

// ---------------- XCD-segmented scatter: packed int2 {col, val_bits} -------
// Same seg/chunk decomposition as k_hist2: all writes to a CSR line come
// from one XCD -> line accumulates in that L2, evicted once.
__global__ __launch_bounds__(256) void k_scat2(
        const int* __restrict__ arow, const int* __restrict__ acol,
        const float* __restrict__ aval, int E,
        const int* __restrict__ prow, const int* __restrict__ pcol,
        const float* __restrict__ pval, int E2,
        int* __restrict__ curA, int2* __restrict__ ccvA,
        int* __restrict__ curP, int2* __restrict__ ccvP, int n) {
    const int seg = blockIdx.x & 7;
    const int seglen = (n + 7) >> 3;
    const int rlo = seg * seglen, rhi = rlo + seglen;
    const int base = (blockIdx.x >> 3) * SCAT_CHUNK;
    const int lim = min(base + SCAT_CHUNK, E + E2);
    for (int i = base + threadIdx.x; i < lim; i += 256) {
        if (i < E) {
            int r = __builtin_nontemporal_load(&arow[i]);
            if (r >= rlo && r < rhi) {
                int c = acol[i];
                float v = aval[i];
                int p = atomicAdd(&curA[r], 1);
                ccvA[p] = make_int2(c, __float_as_int(v));
            }
        } else {
            int j = i - E;
            int r = __builtin_nontemporal_load(&prow[j]);
            if (r >= rlo && r < rhi) {
                int c = pcol[j];
                float v = pval[j];
                int p = atomicAdd(&curP[r], 1);
                ccvP[p] = make_int2(c, __float_as_int(v));
            }
        }
    }
}

// ---------------- GEMM1: xw = bf16(x) @ bf16(W1), MFMA ----------------
__global__ __launch_bounds__(256) void k_gemm1(const float* __restrict__ x,
        const __bf16* __restrict__ W1t, __bf16* __restrict__ xw, int N) {
    __shared__ __align__(16) __bf16 xs[64][64];
    __shared__ __align__(16) __bf16 ws[64][64];
    const int t = threadIdx.x;
    const int lane = t & 63;
    const int w = t >> 6;
    const int wr = (w >> 1) * 32;
    const int wc = (w & 1) * 32;
    const int l15 = lane & 15;
    const int l4  = lane >> 4;
    const int row0 = blockIdx.x * 64;

    f32x4 acc[2][2] = {};

    for (int k0 = 0; k0 < NFEAT; k0 += 64) {
        #pragma unroll
        for (int s = t; s < 512; s += 256) {
            int r = s >> 3, ch = s & 7;
            int gr = row0 + r;
            float v[8] = {0.f,0.f,0.f,0.f,0.f,0.f,0.f,0.f};
            if (gr < N) {
                const float4* p = (const float4*)(x + (size_t)gr * NFEAT + k0 + ch * 8);
                float4 a0 = p[0], a1 = p[1];
                v[0]=a0.x; v[1]=a0.y; v[2]=a0.z; v[3]=a0.w;
                v[4]=a1.x; v[5]=a1.y; v[6]=a1.z; v[7]=a1.w;
            }
            bf16x8 frag;
            #pragma unroll
            for (int j = 0; j < 8; ++j) frag[j] = (__bf16)v[j];
            *(bf16x8*)&xs[r][((ch ^ (r & 7)) * 8)] = frag;
        }
        #pragma unroll
        for (int s = t; s < 512; s += 256) {
            int n = s >> 3, ch = s & 7;
            bf16x8 frag = *(const bf16x8*)(W1t + (size_t)n * NFEAT + k0 + ch * 8);
            *(bf16x8*)&ws[n][((ch ^ (n & 7)) * 8)] = frag;
        }
        __syncthreads();
        #pragma unroll
        for (int kh = 0; kh < 2; ++kh) {
            bf16x8 a[2], b[2];
            #pragma unroll
            for (int mi = 0; mi < 2; ++mi) {
                int r = wr + mi * 16 + l15;
                int ch = (kh * 4 + l4) ^ (r & 7);
                a[mi] = *(const bf16x8*)&xs[r][ch * 8];
            }
            #pragma unroll
            for (int ni = 0; ni < 2; ++ni) {
                int n = wc + ni * 16 + l15;
                int ch = (kh * 4 + l4) ^ (n & 7);
                b[ni] = *(const bf16x8*)&ws[n][ch * 8];
            }
            #pragma unroll
            for (int mi = 0; mi < 2; ++mi)
                #pragma unroll
                for (int ni = 0; ni < 2; ++ni)
                    acc[mi][ni] = __builtin_amdgcn_mfma_f32_16x16x32_bf16(a[mi], b[ni], acc[mi][ni], 0, 0, 0);
        }
        __syncthreads();
    }
    #pragma unroll
    for (int mi = 0; mi < 2; ++mi)
        #pragma unroll
        for (int ni = 0; ni < 2; ++ni)
            #pragma unroll
            for (int j = 0; j < 4; ++j) {
                int r = row0 + wr + mi * 16 + l4 * 4 + j;
                int c = wc + ni * 16 + l15;
                if (r < N) xw[(size_t)r * NHID + c] = (__bf16)acc[mi][ni][j];
            }
}

// ---------------- SPMM1: h1 = relu(adj @ xw + b1) ----------------
__global__ void k_spmm1(const int* __restrict__ rp, const int2* __restrict__ ccv,
        const __bf16* __restrict__ xw, const float* __restrict__ b1,
        float* __restrict__ h1, int N) {
    int lane = threadIdx.x & 63;
    int row = blockIdx.x * 4 + (threadIdx.x >> 6);
    if (row >= N) return;
    int e = rp[row], end = rp[row + 1];
    float acc = 0.f;
    for (; e + 1 < end; e += 2) {
        int2 a = ccv[e], b = ccv[e + 1];
        acc += __int_as_float(a.y) * (float)xw[(size_t)a.x * NHID + lane];
        acc += __int_as_float(b.y) * (float)xw[(size_t)b.x * NHID + lane];
    }
    if (e < end) {
        int2 a = ccv[e];
        acc += __int_as_float(a.y) * (float)xw[(size_t)a.x * NHID + lane];
    }
    h1[(size_t)row * NHID + lane] = fmaxf(acc + b1[lane], 0.f);
}

// ---------------- GEMM2: hw = bf16(h1 @ W2) ----------------
__global__ __launch_bounds__(128) void k_gemm2(const float* __restrict__ h1,
        const float* __restrict__ W2, __bf16* __restrict__ hw, int N) {
    __shared__ float w2s[NHID * NCLASS];
    for (int i = threadIdx.x; i < NHID * NCLASS; i += 128) w2s[i] = W2[i];
    __syncthreads();
    int row = blockIdx.x * 128 + threadIdx.x;
    if (row >= N) return;
    float acc[NCLASS];
    #pragma unroll
    for (int c = 0; c < NCLASS; ++c) acc[c] = 0.f;
    const float4* hp = (const float4*)(h1 + (size_t)row * NHID);
    #pragma unroll
    for (int k4 = 0; k4 < NHID / 4; ++k4) {
        float4 a = hp[k4];
        const float* wr0 = &w2s[(k4 * 4) * NCLASS];
        #pragma unroll
        for (int c = 0; c < NCLASS; ++c)
            acc[c] += a.x * wr0[c] + a.y * wr0[NCLASS + c]
                    + a.z * wr0[2 * NCLASS + c] + a.w * wr0[3 * NCLASS + c];
    }
    // 40 bf16 = 80 B per row, 16B-aligned (80 % 16 == 0): 5 x bf16x8 stores
    bf16x8* op = (bf16x8*)(hw + (size_t)row * NCLASS);
    #pragma unroll
    for (int c8 = 0; c8 < NCLASS / 8; ++c8) {
        bf16x8 o;
        #pragma unroll
        for (int j = 0; j < 8; ++j) o[j] = (__bf16)acc[c8 * 8 + j];
        op[c8] = o;
    }
}

// ---------------- SPMM2: h2 = adj @ hw + b2 ----------------
__global__ void k_spmm2(const int* __restrict__ rp, const int2* __restrict__ ccv,
        const __bf16* __restrict__ hw, const float* __restrict__ b2,
        float* __restrict__ h2, int N) {
    int lane = threadIdx.x & 63;
    int row = blockIdx.x * 4 + (threadIdx.x >> 6);
    if (row >= N) return;
    if (lane >= NCLASS) return;
    int e = rp[row], end = rp[row + 1];
    float acc = 0.f;
    for (; e + 1 < end; e += 2) {
        int2 a = ccv[e], b = ccv[e + 1];
        acc += __int_as_float(a.y) * (float)hw[(size_t)a.x * NCLASS + lane];
        acc += __int_as_float(b.y) * (float)hw[(size_t)b.x * NCLASS + lane];
    }
    if (e < end) {
        int2 a = ccv[e];
        acc += __int_as_float(a.y) * (float)hw[(size_t)a.x * NCLASS + lane];
    }
    h2[(size_t)row * NCLASS + lane] = acc + b2[lane];
}

// ---------------- fused PvT spmm (CSR, no atomics) + log_softmax -----------
__global__ void k_pvt_lsm(const int* __restrict__ rp, const int2* __restrict__ ccv,
        const float* __restrict__ h2, float* __restrict__ out, int N) {
    int lane = threadIdx.x & 63;
    int row = blockIdx.x * 4 + (threadIdx.x >> 6);
    if (row >= N) return;
    float acc = 0.f;
    if (lane < NCLASS) {
        int e = rp[row], end = rp[row + 1];
        for (; e < end; ++e) {
            int2 a = ccv[e];
            acc += __int_as_float(a.y) * h2[(size_t)a.x * NCLASS + lane];
        }
    }
    float v = (lane < NCLASS) ? acc : -__builtin_inff();
    float m = v;
    #pragma unroll
    for (int o = 32; o; o >>= 1) m = fmaxf(m, __shfl_xor(m, o, 64));
    float ex = (lane < NCLASS) ? expf(v - m) : 0.f;
    float s = ex;
    #pragma unroll
    for (int o = 32; o; o >>= 1) s += __shfl_xor(s, o, 64);
    if (lane < NCLASS) out[(size_t)row * NCLASS + lane] = v - m - logf(s);
}

extern "C" void kernel_launch(void* const* d_in, const int* in_sizes, int n_in,
                              void* d_out, int out_size, void* d_ws, size_t ws_size,
                              hipStream_t stream) {
    const float* x       = (const float*)d_in[0];
    const int*   adj_row = (const int*)d_in[1];
    const int*   adj_col = (const int*)d_in[2];
    const float* adj_val = (const float*)d_in[3];
    const int*   pvt_row = (const int*)d_in[4];
    const int*   pvt_col = (const int*)d_in[5];
    const float* pvt_val = (const float*)d_in[6];
    const float* W1      = (const float*)d_in[7];
    const float* b1      = (const float*)d_in[8];
    const float* W2      = (const float*)d_in[9];
    const float* b2      = (const float*)d_in[10];
    const int N  = in_sizes[0] / NFEAT;
    const int E  = in_sizes[1];
    const int E2 = in_sizes[4];
    float* out = (float*)d_out;

    char* p = (char*)d_ws;
    auto alloc = [&](size_t bytes) { char* q = p; p += (bytes + 255) & ~(size_t)255; return q; };
    // unionA: xw (bf16, 12.8MB) then hw (bf16, 8MB)
    char* uA = alloc((size_t)N * NHID * 2);
    __bf16* xw = (__bf16*)uA;
    __bf16* hw = (__bf16*)uA;
    // unionB: h1 (f32, 25.6MB) then h2 (f32, 16MB)
    char* uB = alloc((size_t)N * NHID * 4);
    float* h1 = (float*)uB;
    float* h2 = (float*)uB;
    int*    cnt2 = (int*)alloc((size_t)2 * N * 4);       // cntA | cntP
    int*    cntA = cnt2;
    int*    cntP = cnt2 + N;
    int*    rpA  = (int*)alloc(((size_t)N + 1) * 4);
    int*    rpP  = (int*)alloc(((size_t)N + 1) * 4);
    int*    curA = (int*)alloc((size_t)N * 4);
    int*    curP = (int*)alloc((size_t)N * 4);
    int2*   ccvA = (int2*)alloc((size_t)E * 8);
    int2*   ccvP = (int2*)alloc((size_t)E2 * 8);
    __bf16* W1t  = (__bf16*)alloc((size_t)NFEAT * NHID * 2);
    int*    exclA = (int*)alloc((size_t)N * 4);
    int*    exclP = (int*)alloc((size_t)N * 4);
    const int nblk = (N + 1023) / 1024;
    int*    bsumA = (int*)alloc(((size_t)nblk + 1) * 4);
    int*    bsumP = (int*)alloc(((size_t)nblk + 1) * 4);
    (void)ws_size; (void)n_in; (void)out_size;

    const int nchunk = (E + E2 + SCAT_CHUNK - 1) / SCAT_CHUNK;

    hipMemsetAsync(cnt2, 0, (size_t)2 * N * 4, stream);
    k_w1t<<<(NFEAT * NHID + 255) / 256, 256, 0, stream>>>(W1, W1t);
    k_hist2<<<nchunk * 8, 256, 0, stream>>>(adj_row, E, pvt_row, E2, cntA, cntP, N);
    k_scan1<<<dim3(nblk, 2), 1024, 0, stream>>>(cntA, exclA, bsumA, cntP, exclP, bsumP, N);
    k_scan2<<<2, 1024, 0, stream>>>(bsumA, bsumP, nblk);
    k_scan3<<<dim3(nblk, 2), 1024, 0, stream>>>(exclA, bsumA, rpA, curA,
                                                exclP, bsumP, rpP, curP, N, nblk);
    k_scat2<<<nchunk * 8, 256, 0, stream>>>(adj_row, adj_col, adj_val, E,
                                            pvt_row, pvt_col, pvt_val, E2,
                                            curA, ccvA, curP, ccvP, N);
    k_gemm1<<<(N + 63) / 64, 256, 0, stream>>>(x, W1t, xw, N);
    k_spmm1<<<(N + 3) / 4, 256, 0, stream>>>(rpA, ccvA, xw, b1, h1, N);
    k_gemm2<<<(N + 127) / 128, 128, 0, stream>>>(h1, W2, hw, N);
    k_spmm2<<<(N + 3) / 4, 256, 0, stream>>>(rpA, ccvA, hw, b2, h2, N);
    k_pvt_lsm<<<(N + 3) / 4, 256, 0, stream>>>(rpP, ccvP, h2, out, N);
}